// Round 8
// baseline (311.802 us; speedup 1.0000x reference)
//
#include <hip/hip_runtime.h>
#include <math.h>

#define N_NODES 100000
#define F_IN    128
#define HID     64
#define N_CLS   40
#define MT      (N_NODES / 16)                  // 6250 M-tiles of 16 nodes

#define BSHIFT  9
#define BSZ     512                              // dsts per coarse bucket
#define NB      ((N_NODES + BSZ - 1) / BSZ)      // 196 buckets
#define EPB     4096                             // edges per block in sort passes

typedef __attribute__((ext_vector_type(8))) short bf8_t;   // 8 bf16 (4 VGPR)
typedef __attribute__((ext_vector_type(4))) float f4_t;    // MFMA C/D frag

typedef unsigned short ushort_t;
typedef unsigned int uint_t;

__device__ __forceinline__ ushort_t f2b(float f) {   // f32 -> bf16 RNE
    union { float f; uint_t u; } c; c.f = f;
    uint_t u = c.u + 0x7FFFu + ((c.u >> 16) & 1u);
    return (ushort_t)(u >> 16);
}
__device__ __forceinline__ float b2f(ushort_t h) {
    union { uint_t u; float f; } c; c.u = ((uint_t)h) << 16;
    return c.f;
}

// ---------------------------------------------------------------------------
// Sort pass 1: per-block LDS histogram over 196 coarse buckets (dst >> 9).
// ---------------------------------------------------------------------------
__global__ void block_hist_kernel(const int* __restrict__ ei, int E,
                                  int* __restrict__ blockHist) {
    __shared__ int cnt[NB];
    int t = threadIdx.x, blk = blockIdx.x;
    for (int i = t; i < NB; i += 256) cnt[i] = 0;
    __syncthreads();
    int e0 = blk * EPB;
#pragma unroll
    for (int i = 0; i < EPB / 256; ++i) {
        int e = e0 + i * 256 + t;
        if (e < E) atomicAdd(&cnt[ei[E + e] >> BSHIFT], 1);
    }
    __syncthreads();
    for (int i = t; i < NB; i += 256) blockHist[blk * NB + i] = cnt[i];
}

// ---------------------------------------------------------------------------
// Sort pass 2: per-bin exclusive scan down the blocks.
// ---------------------------------------------------------------------------
__global__ void col_scan_kernel(const int* __restrict__ blockHist, int nblk,
                                int* __restrict__ blockBase,
                                int* __restrict__ btot) {
    __shared__ int ss[256];
    __shared__ int carry;
    int bin = blockIdx.x, t = threadIdx.x;
    if (t == 0) carry = 0;
    __syncthreads();
    for (int c0 = 0; c0 < nblk; c0 += 256) {
        int b = c0 + t;
        int v = (b < nblk) ? blockHist[b * NB + bin] : 0;
        ss[t] = v;
        __syncthreads();
        for (int off = 1; off < 256; off <<= 1) {
            int u = (t >= off) ? ss[t - off] : 0;
            __syncthreads();
            ss[t] += u;
            __syncthreads();
        }
        if (b < nblk) blockBase[b * NB + bin] = carry + ss[t] - v;
        __syncthreads();
        if (t == 255) carry += ss[255];
        __syncthreads();
    }
    if (t == 0) btot[bin] = carry;
}

// ---------------------------------------------------------------------------
// Sort pass 3: exclusive scan over 196 bucket totals; rowptr[N] = E.
// ---------------------------------------------------------------------------
__global__ void bucket_scan_kernel(const int* __restrict__ btot,
                                   int* __restrict__ boff,
                                   int* __restrict__ rowptr) {
    __shared__ int ss[256];
    int t = threadIdx.x;
    int v = (t < NB) ? btot[t] : 0;
    ss[t] = v;
    __syncthreads();
    for (int off = 1; off < 256; off <<= 1) {
        int u = (t >= off) ? ss[t - off] : 0;
        __syncthreads();
        ss[t] += u;
        __syncthreads();
    }
    if (t < NB) boff[t] = ss[t] - v;
    if (t == NB - 1) rowptr[N_NODES] = ss[t];
}

// ---------------------------------------------------------------------------
// Sort pass 4: scatter packed (src<<9 | dst&511) into coarse-bucket order.
// ---------------------------------------------------------------------------
__global__ void scatter_pairs_kernel(const int* __restrict__ ei, int E,
                                     const int* __restrict__ blockBase,
                                     const int* __restrict__ boff,
                                     uint_t* __restrict__ pairs) {
    __shared__ int cur[NB];
    __shared__ int base[NB];
    int t = threadIdx.x, blk = blockIdx.x;
    for (int i = t; i < NB; i += 256) {
        cur[i] = 0;
        base[i] = boff[i] + blockBase[blk * NB + i];
    }
    __syncthreads();
    int e0 = blk * EPB;
#pragma unroll
    for (int i = 0; i < EPB / 256; ++i) {
        int e = e0 + i * 256 + t;
        if (e < E) {
            int src = ei[e];
            int dst = ei[E + e];
            int bin = dst >> BSHIFT;
            int r = atomicAdd(&cur[bin], 1);   // LDS atomic
            pairs[base[bin] + r] = ((uint_t)src << BSHIFT) | (uint_t)(dst & (BSZ - 1));
        }
    }
}

// ---------------------------------------------------------------------------
// Sort pass 5: per-bucket fine sort. rowptr + contiguous csr region.
// ---------------------------------------------------------------------------
__global__ void bucket_sort_kernel(const uint_t* __restrict__ pairs,
                                   const int* __restrict__ boff,
                                   const int* __restrict__ btot,
                                   int* __restrict__ rowptr,
                                   int* __restrict__ csr) {
    __shared__ int hist[BSZ];
    __shared__ int lofs[BSZ];
    int bin = blockIdx.x, t = threadIdx.x;
    int base = boff[bin], cnt = btot[bin];
    hist[t] = 0;
    __syncthreads();
    for (int i = t; i < cnt; i += BSZ)
        atomicAdd(&hist[pairs[base + i] & (BSZ - 1)], 1);
    __syncthreads();
    int v = hist[t];
    lofs[t] = v;
    __syncthreads();
    for (int off = 1; off < BSZ; off <<= 1) {
        int u = (t >= off) ? lofs[t - off] : 0;
        __syncthreads();
        lofs[t] += u;
        __syncthreads();
    }
    int excl = lofs[t] - v;
    int d_global = (bin << BSHIFT) + t;
    if (d_global < N_NODES) rowptr[d_global] = base + excl;
    __syncthreads();
    lofs[t] = excl;
    hist[t] = 0;
    __syncthreads();
    for (int i = t; i < cnt; i += BSZ) {
        uint_t p = pairs[base + i];
        int lb = p & (BSZ - 1);
        int r = atomicAdd(&hist[lb], 1);
        csr[base + lofs[lb] + r] = (int)(p >> BSHIFT);
    }
}

// ---------------------------------------------------------------------------
// cvt_w: bf16 [n][k]-major weight tensors.
// ---------------------------------------------------------------------------
__global__ void cvt_w_kernel(const float* __restrict__ W1l,
                             const float* __restrict__ W1r,
                             const float* __restrict__ W2l,
                             const float* __restrict__ W2r,
                             ushort_t* __restrict__ W1t,
                             ushort_t* __restrict__ W2t) {
    int t = blockIdx.x * blockDim.x + threadIdx.x;
    if (t < 128 * F_IN) {
        int n = t / F_IN, k = t - n * F_IN;
        float v = (n < HID) ? W1l[k * HID + n] : W1r[k * HID + (n - HID)];
        W1t[t] = f2b(v);
    } else if (t < 128 * F_IN + 80 * HID) {
        int u = t - 128 * F_IN;
        int n = u / HID, k = u - n * HID;
        float v = (n < N_CLS) ? W2l[k * N_CLS + n] : W2r[k * N_CLS + (n - N_CLS)];
        W2t[u] = f2b(v);
    }
}

// ---------------------------------------------------------------------------
// gemm1_mfma: [y1b|z1b] = x @ [W1_l|W1_r]  via mfma_f32_16x16x32_bf16.
// ---------------------------------------------------------------------------
__global__ void gemm1_mfma_kernel(const float* __restrict__ x,
                                  const ushort_t* __restrict__ W1t,
                                  ushort_t* __restrict__ y1b,
                                  ushort_t* __restrict__ z1b) {
    int gid = blockIdx.x * blockDim.x + threadIdx.x;
    int wave = gid >> 6, lane = gid & 63;
    if (wave >= MT) return;
    int m0 = wave * 16;
    int r = lane & 15, q = lane >> 4;

    const float* xr = x + (size_t)(m0 + r) * F_IN + q * 8;
    bf8_t a[4];
#pragma unroll
    for (int kt = 0; kt < 4; ++kt) {
        float4 u = *(const float4*)(xr + kt * 32);
        float4 v = *(const float4*)(xr + kt * 32 + 4);
        bf8_t t;
        t[0] = (short)f2b(u.x); t[1] = (short)f2b(u.y);
        t[2] = (short)f2b(u.z); t[3] = (short)f2b(u.w);
        t[4] = (short)f2b(v.x); t[5] = (short)f2b(v.y);
        t[6] = (short)f2b(v.z); t[7] = (short)f2b(v.w);
        a[kt] = t;
    }
#pragma unroll
    for (int tn = 0; tn < 8; ++tn) {
        const ushort_t* wr = W1t + (size_t)(tn * 16 + r) * F_IN + q * 8;
        f4_t acc = {0.f, 0.f, 0.f, 0.f};
#pragma unroll
        for (int kt = 0; kt < 4; ++kt) {
            bf8_t b = *(const bf8_t*)(wr + kt * 32);
            acc = __builtin_amdgcn_mfma_f32_16x16x32_bf16(a[kt], b, acc, 0, 0, 0);
        }
        int col = tn * 16 + r;
        ushort_t* dst = (col < HID) ? (y1b + col) : (z1b + (col - HID));
#pragma unroll
        for (int rr = 0; rr < 4; ++rr) {
            int row = m0 + q * 4 + rr;
            dst[(size_t)row * HID] = f2b(acc[rr]);
        }
    }
}

// ---------------------------------------------------------------------------
// agg1: h = relu(mean y1[src] + b1 + z1).  4 edge-groups of 16 lanes;
// 4-deep unroll -> 16 row-fetches in flight per wave.
// ---------------------------------------------------------------------------
__global__ void agg1_kernel(const int* __restrict__ rowptr,
                            const int* __restrict__ csr,
                            const ushort_t* __restrict__ y1b,
                            const ushort_t* __restrict__ z1b,
                            const float* __restrict__ b1,
                            ushort_t* __restrict__ hb) {
    int gid = blockIdx.x * blockDim.x + threadIdx.x;
    int n = gid >> 6;
    int lane = gid & 63;
    if (n >= N_NODES) return;
    int g = lane >> 4, l = lane & 15;
    int beg = rowptr[n], end = rowptr[n + 1];
    float a0 = 0.f, a1 = 0.f, a2 = 0.f, a3 = 0.f;
    int i = beg + g;
    for (; i + 12 < end; i += 16) {      // 4 rows in flight per group
        int s0 = csr[i], s1 = csr[i + 4], s2 = csr[i + 8], s3 = csr[i + 12];
        ushort4 v0 = *(const ushort4*)(y1b + (size_t)s0 * HID + l * 4);
        ushort4 v1 = *(const ushort4*)(y1b + (size_t)s1 * HID + l * 4);
        ushort4 v2 = *(const ushort4*)(y1b + (size_t)s2 * HID + l * 4);
        ushort4 v3 = *(const ushort4*)(y1b + (size_t)s3 * HID + l * 4);
        a0 += (b2f(v0.x) + b2f(v1.x)) + (b2f(v2.x) + b2f(v3.x));
        a1 += (b2f(v0.y) + b2f(v1.y)) + (b2f(v2.y) + b2f(v3.y));
        a2 += (b2f(v0.z) + b2f(v1.z)) + (b2f(v2.z) + b2f(v3.z));
        a3 += (b2f(v0.w) + b2f(v1.w)) + (b2f(v2.w) + b2f(v3.w));
    }
    for (; i < end; i += 4) {
        ushort4 v = *(const ushort4*)(y1b + (size_t)csr[i] * HID + l * 4);
        a0 += b2f(v.x); a1 += b2f(v.y); a2 += b2f(v.z); a3 += b2f(v.w);
    }
    a0 += __shfl_xor(a0, 16, 64); a0 += __shfl_xor(a0, 32, 64);
    a1 += __shfl_xor(a1, 16, 64); a1 += __shfl_xor(a1, 32, 64);
    a2 += __shfl_xor(a2, 16, 64); a2 += __shfl_xor(a2, 32, 64);
    a3 += __shfl_xor(a3, 16, 64); a3 += __shfl_xor(a3, 32, 64);

    if (g == 0) {
        float inv = 1.0f / fmaxf((float)(end - beg), 1.0f);
        float4 bb = *(const float4*)(b1 + l * 4);
        ushort4 zz = *(const ushort4*)(z1b + (size_t)n * HID + l * 4);
        float r0 = fmaxf(fmaf(a0, inv, bb.x + b2f(zz.x)), 0.f);
        float r1 = fmaxf(fmaf(a1, inv, bb.y + b2f(zz.y)), 0.f);
        float r2 = fmaxf(fmaf(a2, inv, bb.z + b2f(zz.z)), 0.f);
        float r3 = fmaxf(fmaf(a3, inv, bb.w + b2f(zz.w)), 0.f);
        ushort4 o;
        o.x = f2b(r0); o.y = f2b(r1); o.z = f2b(r2); o.w = f2b(r3);
        *(ushort4*)(hb + (size_t)n * HID + l * 4) = o;
    }
}

// ---------------------------------------------------------------------------
// gemm2_mfma: [y2b|z2b] = h @ [W2_l|W2_r], outputs PADDED to stride 64.
// ---------------------------------------------------------------------------
__global__ void gemm2_mfma_kernel(const ushort_t* __restrict__ hb,
                                  const ushort_t* __restrict__ W2t,
                                  ushort_t* __restrict__ y2b,
                                  ushort_t* __restrict__ z2b) {
    int gid = blockIdx.x * blockDim.x + threadIdx.x;
    int wave = gid >> 6, lane = gid & 63;
    if (wave >= MT) return;
    int m0 = wave * 16;
    int r = lane & 15, q = lane >> 4;

    const ushort_t* hr = hb + (size_t)(m0 + r) * HID + q * 8;
    bf8_t a[2];
#pragma unroll
    for (int kt = 0; kt < 2; ++kt)
        a[kt] = *(const bf8_t*)(hr + kt * 32);

#pragma unroll
    for (int tn = 0; tn < 5; ++tn) {
        const ushort_t* wr = W2t + (size_t)(tn * 16 + r) * HID + q * 8;
        f4_t acc = {0.f, 0.f, 0.f, 0.f};
#pragma unroll
        for (int kt = 0; kt < 2; ++kt) {
            bf8_t b = *(const bf8_t*)(wr + kt * 32);
            acc = __builtin_amdgcn_mfma_f32_16x16x32_bf16(a[kt], b, acc, 0, 0, 0);
        }
        int col = tn * 16 + r;
        ushort_t* dst = (col < N_CLS) ? (y2b + col) : (z2b + (col - N_CLS));
#pragma unroll
        for (int rr = 0; rr < 4; ++rr) {
            int row = m0 + q * 4 + rr;
            dst[(size_t)row * HID] = f2b(acc[rr]);   // stride 64 (padded)
        }
    }
}

// ---------------------------------------------------------------------------
// agg2 + log_softmax. Same 4-group, 4-deep structure; pad cols masked.
// ---------------------------------------------------------------------------
__global__ void agg2_kernel(const int* __restrict__ rowptr,
                            const int* __restrict__ csr,
                            const ushort_t* __restrict__ y2b,
                            const ushort_t* __restrict__ z2b,
                            const float* __restrict__ b2,
                            float* __restrict__ out) {
    int gid = blockIdx.x * blockDim.x + threadIdx.x;
    int n = gid >> 6;
    int lane = gid & 63;
    if (n >= N_NODES) return;
    int g = lane >> 4, l = lane & 15;
    int beg = rowptr[n], end = rowptr[n + 1];
    float a0 = 0.f, a1 = 0.f, a2 = 0.f, a3 = 0.f;
    int i = beg + g;
    for (; i + 12 < end; i += 16) {
        int s0 = csr[i], s1 = csr[i + 4], s2 = csr[i + 8], s3 = csr[i + 12];
        ushort4 v0 = *(const ushort4*)(y2b + (size_t)s0 * HID + l * 4);
        ushort4 v1 = *(const ushort4*)(y2b + (size_t)s1 * HID + l * 4);
        ushort4 v2 = *(const ushort4*)(y2b + (size_t)s2 * HID + l * 4);
        ushort4 v3 = *(const ushort4*)(y2b + (size_t)s3 * HID + l * 4);
        a0 += (b2f(v0.x) + b2f(v1.x)) + (b2f(v2.x) + b2f(v3.x));
        a1 += (b2f(v0.y) + b2f(v1.y)) + (b2f(v2.y) + b2f(v3.y));
        a2 += (b2f(v0.z) + b2f(v1.z)) + (b2f(v2.z) + b2f(v3.z));
        a3 += (b2f(v0.w) + b2f(v1.w)) + (b2f(v2.w) + b2f(v3.w));
    }
    for (; i < end; i += 4) {
        ushort4 v = *(const ushort4*)(y2b + (size_t)csr[i] * HID + l * 4);
        a0 += b2f(v.x); a1 += b2f(v.y); a2 += b2f(v.z); a3 += b2f(v.w);
    }
    a0 += __shfl_xor(a0, 16, 64); a0 += __shfl_xor(a0, 32, 64);
    a1 += __shfl_xor(a1, 16, 64); a1 += __shfl_xor(a1, 32, 64);
    a2 += __shfl_xor(a2, 16, 64); a2 += __shfl_xor(a2, 32, 64);
    a3 += __shfl_xor(a3, 16, 64); a3 += __shfl_xor(a3, 32, 64);

    float inv = 1.0f / fmaxf((float)(end - beg), 1.0f);
    int c0 = l * 4;
    float4 bb = (l < 10) ? *(const float4*)(b2 + c0)
                         : make_float4(0.f, 0.f, 0.f, 0.f);
    ushort4 zz = *(const ushort4*)(z2b + (size_t)n * HID + c0);
    float v0 = (c0 + 0 < N_CLS) ? fmaf(a0, inv, bb.x + b2f(zz.x)) : -INFINITY;
    float v1 = (c0 + 1 < N_CLS) ? fmaf(a1, inv, bb.y + b2f(zz.y)) : -INFINITY;
    float v2 = (c0 + 2 < N_CLS) ? fmaf(a2, inv, bb.z + b2f(zz.z)) : -INFINITY;
    float v3 = (c0 + 3 < N_CLS) ? fmaf(a3, inv, bb.w + b2f(zz.w)) : -INFINITY;

    float m = fmaxf(fmaxf(v0, v1), fmaxf(v2, v3));
#pragma unroll
    for (int off = 1; off < 16; off <<= 1)
        m = fmaxf(m, __shfl_xor(m, off, 64));
    float s = 0.f;
    if (v0 > -INFINITY) s += expf(v0 - m);
    if (v1 > -INFINITY) s += expf(v1 - m);
    if (v2 > -INFINITY) s += expf(v2 - m);
    if (v3 > -INFINITY) s += expf(v3 - m);
#pragma unroll
    for (int off = 1; off < 16; off <<= 1)
        s += __shfl_xor(s, off, 64);
    float ls = logf(s);
    if (g == 0 && l < 10) {
        float4 o = make_float4(v0 - m - ls, v1 - m - ls, v2 - m - ls, v3 - m - ls);
        *(float4*)(out + (size_t)n * N_CLS + c0) = o;
    }
}

extern "C" void kernel_launch(void* const* d_in, const int* in_sizes, int n_in,
                              void* d_out, int out_size, void* d_ws, size_t ws_size,
                              hipStream_t stream) {
    const float* x   = (const float*)d_in[0];
    const int*   ei  = (const int*)d_in[1];
    const float* W1l = (const float*)d_in[2];
    const float* b1  = (const float*)d_in[3];
    const float* W1r = (const float*)d_in[4];
    const float* W2l = (const float*)d_in[5];
    const float* b2  = (const float*)d_in[6];
    const float* W2r = (const float*)d_in[7];
    float* out = (float*)d_out;
    const int E = in_sizes[1] / 2;
    const int nblk = (E + EPB - 1) / EPB;

    char* p = (char*)d_ws;
    auto take = [&](size_t bytes) {
        char* q = p;
        p += (bytes + 15) & ~(size_t)15;
        return (void*)q;
    };
    int* rowptr     = (int*)take(sizeof(int) * (N_NODES + 4));
    int* blockHist  = (int*)take(sizeof(int) * (size_t)nblk * NB);
    int* blockBase  = (int*)take(sizeof(int) * (size_t)nblk * NB);
    int* btot       = (int*)take(sizeof(int) * NB);
    int* boff       = (int*)take(sizeof(int) * NB);
    uint_t* pairs   = (uint_t*)take(sizeof(uint_t) * (size_t)E);
    int* csr        = (int*)take(sizeof(int) * (size_t)E);
    ushort_t* W1t   = (ushort_t*)take(sizeof(ushort_t) * 128 * F_IN);
    ushort_t* W2t   = (ushort_t*)take(sizeof(ushort_t) * 80 * HID);
    ushort_t* y1b   = (ushort_t*)take(sizeof(ushort_t) * (size_t)N_NODES * HID);
    ushort_t* z1b   = (ushort_t*)take(sizeof(ushort_t) * (size_t)N_NODES * HID);
    ushort_t* hb    = (ushort_t*)take(sizeof(ushort_t) * (size_t)N_NODES * HID);
    ushort_t* y2b = y1b;   // stride-64 padded; y1b/z1b dead after agg1
    ushort_t* z2b = z1b;

    const int B = 256;

    block_hist_kernel<<<nblk, 256, 0, stream>>>(ei, E, blockHist);
    col_scan_kernel<<<NB, 256, 0, stream>>>(blockHist, nblk, blockBase, btot);
    bucket_scan_kernel<<<1, 256, 0, stream>>>(btot, boff, rowptr);
    scatter_pairs_kernel<<<nblk, 256, 0, stream>>>(ei, E, blockBase, boff, pairs);
    bucket_sort_kernel<<<NB, BSZ, 0, stream>>>(pairs, boff, btot, rowptr, csr);

    cvt_w_kernel<<<(128 * F_IN + 80 * HID + B - 1) / B, B, 0, stream>>>(
        W1l, W1r, W2l, W2r, W1t, W2t);

    int t_mfma = MT * 64;
    int t_nodes64 = N_NODES * 64;

    gemm1_mfma_kernel<<<(t_mfma + B - 1) / B, B, 0, stream>>>(x, W1t, y1b, z1b);
    agg1_kernel<<<(t_nodes64 + B - 1) / B, B, 0, stream>>>(rowptr, csr, y1b, z1b, b1, hb);
    gemm2_mfma_kernel<<<(t_mfma + B - 1) / B, B, 0, stream>>>(hb, W2t, y2b, z2b);
    agg2_kernel<<<(t_nodes64 + B - 1) / B, B, 0, stream>>>(rowptr, csr, y2b, z2b, b2, out);
}

// Round 9
// 304.985 us; speedup vs baseline: 1.0224x; 1.0224x over previous
//
#include <hip/hip_runtime.h>
#include <math.h>

#define N_NODES 100000
#define F_IN    128
#define HID     64
#define N_CLS   40
#define MT      (N_NODES / 16)                  // 6250 M-tiles of 16 nodes

#define BSHIFT  9
#define BSZ     512                              // dsts per coarse bucket
#define NB      ((N_NODES + BSZ - 1) / BSZ)      // 196 buckets
#define EPB     4096                             // edges per block in sort passes

typedef __attribute__((ext_vector_type(8))) short bf8_t;   // 8 bf16 (4 VGPR)
typedef __attribute__((ext_vector_type(4))) float f4_t;    // MFMA C/D frag

typedef unsigned short ushort_t;
typedef unsigned int uint_t;

__device__ __forceinline__ ushort_t f2b(float f) {   // f32 -> bf16 RNE
    union { float f; uint_t u; } c; c.f = f;
    uint_t u = c.u + 0x7FFFu + ((c.u >> 16) & 1u);
    return (ushort_t)(u >> 16);
}
__device__ __forceinline__ float b2f(ushort_t h) {
    union { uint_t u; float f; } c; c.u = ((uint_t)h) << 16;
    return c.f;
}

// ---------------------------------------------------------------------------
// Sort pass 1: per-block LDS histogram over 196 coarse buckets (dst >> 9).
// ---------------------------------------------------------------------------
__global__ void block_hist_kernel(const int* __restrict__ ei, int E,
                                  int* __restrict__ blockHist) {
    __shared__ int cnt[NB];
    int t = threadIdx.x, blk = blockIdx.x;
    for (int i = t; i < NB; i += 256) cnt[i] = 0;
    __syncthreads();
    int e0 = blk * EPB;
#pragma unroll
    for (int i = 0; i < EPB / 256; ++i) {
        int e = e0 + i * 256 + t;
        if (e < E) atomicAdd(&cnt[ei[E + e] >> BSHIFT], 1);
    }
    __syncthreads();
    for (int i = t; i < NB; i += 256) blockHist[blk * NB + i] = cnt[i];
}

// ---------------------------------------------------------------------------
// Sort pass 2: per-bin exclusive scan down the blocks.
// ---------------------------------------------------------------------------
__global__ void col_scan_kernel(const int* __restrict__ blockHist, int nblk,
                                int* __restrict__ blockBase,
                                int* __restrict__ btot) {
    __shared__ int ss[256];
    __shared__ int carry;
    int bin = blockIdx.x, t = threadIdx.x;
    if (t == 0) carry = 0;
    __syncthreads();
    for (int c0 = 0; c0 < nblk; c0 += 256) {
        int b = c0 + t;
        int v = (b < nblk) ? blockHist[b * NB + bin] : 0;
        ss[t] = v;
        __syncthreads();
        for (int off = 1; off < 256; off <<= 1) {
            int u = (t >= off) ? ss[t - off] : 0;
            __syncthreads();
            ss[t] += u;
            __syncthreads();
        }
        if (b < nblk) blockBase[b * NB + bin] = carry + ss[t] - v;
        __syncthreads();
        if (t == 255) carry += ss[255];
        __syncthreads();
    }
    if (t == 0) btot[bin] = carry;
}

// ---------------------------------------------------------------------------
// Sort pass 3: exclusive scan over 196 bucket totals; rowptr[N] = E.
// ---------------------------------------------------------------------------
__global__ void bucket_scan_kernel(const int* __restrict__ btot,
                                   int* __restrict__ boff,
                                   int* __restrict__ rowptr) {
    __shared__ int ss[256];
    int t = threadIdx.x;
    int v = (t < NB) ? btot[t] : 0;
    ss[t] = v;
    __syncthreads();
    for (int off = 1; off < 256; off <<= 1) {
        int u = (t >= off) ? ss[t - off] : 0;
        __syncthreads();
        ss[t] += u;
        __syncthreads();
    }
    if (t < NB) boff[t] = ss[t] - v;
    if (t == NB - 1) rowptr[N_NODES] = ss[t];
}

// ---------------------------------------------------------------------------
// Sort pass 4: scatter packed (src<<9 | dst&511) into coarse-bucket order.
// ---------------------------------------------------------------------------
__global__ void scatter_pairs_kernel(const int* __restrict__ ei, int E,
                                     const int* __restrict__ blockBase,
                                     const int* __restrict__ boff,
                                     uint_t* __restrict__ pairs) {
    __shared__ int cur[NB];
    __shared__ int base[NB];
    int t = threadIdx.x, blk = blockIdx.x;
    for (int i = t; i < NB; i += 256) {
        cur[i] = 0;
        base[i] = boff[i] + blockBase[blk * NB + i];
    }
    __syncthreads();
    int e0 = blk * EPB;
#pragma unroll
    for (int i = 0; i < EPB / 256; ++i) {
        int e = e0 + i * 256 + t;
        if (e < E) {
            int src = ei[e];
            int dst = ei[E + e];
            int bin = dst >> BSHIFT;
            int r = atomicAdd(&cur[bin], 1);   // LDS atomic
            pairs[base[bin] + r] = ((uint_t)src << BSHIFT) | (uint_t)(dst & (BSZ - 1));
        }
    }
}

// ---------------------------------------------------------------------------
// Sort pass 5: per-bucket fine sort. rowptr + contiguous csr region.
// ---------------------------------------------------------------------------
__global__ void bucket_sort_kernel(const uint_t* __restrict__ pairs,
                                   const int* __restrict__ boff,
                                   const int* __restrict__ btot,
                                   int* __restrict__ rowptr,
                                   int* __restrict__ csr) {
    __shared__ int hist[BSZ];
    __shared__ int lofs[BSZ];
    int bin = blockIdx.x, t = threadIdx.x;
    int base = boff[bin], cnt = btot[bin];
    hist[t] = 0;
    __syncthreads();
    for (int i = t; i < cnt; i += BSZ)
        atomicAdd(&hist[pairs[base + i] & (BSZ - 1)], 1);
    __syncthreads();
    int v = hist[t];
    lofs[t] = v;
    __syncthreads();
    for (int off = 1; off < BSZ; off <<= 1) {
        int u = (t >= off) ? lofs[t - off] : 0;
        __syncthreads();
        lofs[t] += u;
        __syncthreads();
    }
    int excl = lofs[t] - v;
    int d_global = (bin << BSHIFT) + t;
    if (d_global < N_NODES) rowptr[d_global] = base + excl;
    __syncthreads();
    lofs[t] = excl;
    hist[t] = 0;
    __syncthreads();
    for (int i = t; i < cnt; i += BSZ) {
        uint_t p = pairs[base + i];
        int lb = p & (BSZ - 1);
        int r = atomicAdd(&hist[lb], 1);
        csr[base + lofs[lb] + r] = (int)(p >> BSHIFT);
    }
}

// ---------------------------------------------------------------------------
// cvt_w: bf16 [n][k]-major weight tensors.
// ---------------------------------------------------------------------------
__global__ void cvt_w_kernel(const float* __restrict__ W1l,
                             const float* __restrict__ W1r,
                             const float* __restrict__ W2l,
                             const float* __restrict__ W2r,
                             ushort_t* __restrict__ W1t,
                             ushort_t* __restrict__ W2t) {
    int t = blockIdx.x * blockDim.x + threadIdx.x;
    if (t < 128 * F_IN) {
        int n = t / F_IN, k = t - n * F_IN;
        float v = (n < HID) ? W1l[k * HID + n] : W1r[k * HID + (n - HID)];
        W1t[t] = f2b(v);
    } else if (t < 128 * F_IN + 80 * HID) {
        int u = t - 128 * F_IN;
        int n = u / HID, k = u - n * HID;
        float v = (n < N_CLS) ? W2l[k * N_CLS + n] : W2r[k * N_CLS + (n - N_CLS)];
        W2t[u] = f2b(v);
    }
}

// ---------------------------------------------------------------------------
// gemm1_mfma: [y1b|z1b] = x @ [W1_l|W1_r]  via mfma_f32_16x16x32_bf16.
// ---------------------------------------------------------------------------
__global__ void gemm1_mfma_kernel(const float* __restrict__ x,
                                  const ushort_t* __restrict__ W1t,
                                  ushort_t* __restrict__ y1b,
                                  ushort_t* __restrict__ z1b) {
    int gid = blockIdx.x * blockDim.x + threadIdx.x;
    int wave = gid >> 6, lane = gid & 63;
    if (wave >= MT) return;
    int m0 = wave * 16;
    int r = lane & 15, q = lane >> 4;

    const float* xr = x + (size_t)(m0 + r) * F_IN + q * 8;
    bf8_t a[4];
#pragma unroll
    for (int kt = 0; kt < 4; ++kt) {
        float4 u = *(const float4*)(xr + kt * 32);
        float4 v = *(const float4*)(xr + kt * 32 + 4);
        bf8_t t;
        t[0] = (short)f2b(u.x); t[1] = (short)f2b(u.y);
        t[2] = (short)f2b(u.z); t[3] = (short)f2b(u.w);
        t[4] = (short)f2b(v.x); t[5] = (short)f2b(v.y);
        t[6] = (short)f2b(v.z); t[7] = (short)f2b(v.w);
        a[kt] = t;
    }
#pragma unroll
    for (int tn = 0; tn < 8; ++tn) {
        const ushort_t* wr = W1t + (size_t)(tn * 16 + r) * F_IN + q * 8;
        f4_t acc = {0.f, 0.f, 0.f, 0.f};
#pragma unroll
        for (int kt = 0; kt < 4; ++kt) {
            bf8_t b = *(const bf8_t*)(wr + kt * 32);
            acc = __builtin_amdgcn_mfma_f32_16x16x32_bf16(a[kt], b, acc, 0, 0, 0);
        }
        int col = tn * 16 + r;
        ushort_t* dst = (col < HID) ? (y1b + col) : (z1b + (col - HID));
#pragma unroll
        for (int rr = 0; rr < 4; ++rr) {
            int row = m0 + q * 4 + rr;
            dst[(size_t)row * HID] = f2b(acc[rr]);
        }
    }
}

// ---------------------------------------------------------------------------
// agg1: h = relu(mean y1[src] + b1 + z1).
// ONE 16-LANE GROUP = ONE NODE (4 nodes/wave). Group walks its node's whole
// edge list (2-deep unroll ~ deg/2 trips); lane l owns columns 4l..4l+3.
// No cross-group shuffles; epilogue all-lanes-active serving 4 nodes.
// ---------------------------------------------------------------------------
__global__ void agg1_kernel(const int* __restrict__ rowptr,
                            const int* __restrict__ csr,
                            const ushort_t* __restrict__ y1b,
                            const ushort_t* __restrict__ z1b,
                            const float* __restrict__ b1,
                            ushort_t* __restrict__ hb) {
    int gid = blockIdx.x * blockDim.x + threadIdx.x;
    int wave = gid >> 6, lane = gid & 63;
    int g = lane >> 4, l = lane & 15;
    int n = wave * 4 + g;                 // N_NODES % 4 == 0
    if (n >= N_NODES) return;
    int beg = rowptr[n], end = rowptr[n + 1];
    float a0 = 0.f, a1 = 0.f, a2 = 0.f, a3 = 0.f;
    int i = beg;
    for (; i + 1 < end; i += 2) {
        int s0 = csr[i], s1 = csr[i + 1];
        ushort4 v0 = *(const ushort4*)(y1b + (size_t)s0 * HID + l * 4);
        ushort4 v1 = *(const ushort4*)(y1b + (size_t)s1 * HID + l * 4);
        a0 += b2f(v0.x) + b2f(v1.x);
        a1 += b2f(v0.y) + b2f(v1.y);
        a2 += b2f(v0.z) + b2f(v1.z);
        a3 += b2f(v0.w) + b2f(v1.w);
    }
    if (i < end) {
        ushort4 v = *(const ushort4*)(y1b + (size_t)csr[i] * HID + l * 4);
        a0 += b2f(v.x); a1 += b2f(v.y); a2 += b2f(v.z); a3 += b2f(v.w);
    }
    float inv = 1.0f / fmaxf((float)(end - beg), 1.0f);
    float4 bb = *(const float4*)(b1 + l * 4);
    ushort4 zz = *(const ushort4*)(z1b + (size_t)n * HID + l * 4);
    float r0 = fmaxf(fmaf(a0, inv, bb.x + b2f(zz.x)), 0.f);
    float r1 = fmaxf(fmaf(a1, inv, bb.y + b2f(zz.y)), 0.f);
    float r2 = fmaxf(fmaf(a2, inv, bb.z + b2f(zz.z)), 0.f);
    float r3 = fmaxf(fmaf(a3, inv, bb.w + b2f(zz.w)), 0.f);
    ushort4 o;
    o.x = f2b(r0); o.y = f2b(r1); o.z = f2b(r2); o.w = f2b(r3);
    *(ushort4*)(hb + (size_t)n * HID + l * 4) = o;
}

// ---------------------------------------------------------------------------
// gemm2_mfma: [y2b|z2b] = h @ [W2_l|W2_r], outputs PADDED to stride 64.
// ---------------------------------------------------------------------------
__global__ void gemm2_mfma_kernel(const ushort_t* __restrict__ hb,
                                  const ushort_t* __restrict__ W2t,
                                  ushort_t* __restrict__ y2b,
                                  ushort_t* __restrict__ z2b) {
    int gid = blockIdx.x * blockDim.x + threadIdx.x;
    int wave = gid >> 6, lane = gid & 63;
    if (wave >= MT) return;
    int m0 = wave * 16;
    int r = lane & 15, q = lane >> 4;

    const ushort_t* hr = hb + (size_t)(m0 + r) * HID + q * 8;
    bf8_t a[2];
#pragma unroll
    for (int kt = 0; kt < 2; ++kt)
        a[kt] = *(const bf8_t*)(hr + kt * 32);

#pragma unroll
    for (int tn = 0; tn < 5; ++tn) {
        const ushort_t* wr = W2t + (size_t)(tn * 16 + r) * HID + q * 8;
        f4_t acc = {0.f, 0.f, 0.f, 0.f};
#pragma unroll
        for (int kt = 0; kt < 2; ++kt) {
            bf8_t b = *(const bf8_t*)(wr + kt * 32);
            acc = __builtin_amdgcn_mfma_f32_16x16x32_bf16(a[kt], b, acc, 0, 0, 0);
        }
        int col = tn * 16 + r;
        ushort_t* dst = (col < N_CLS) ? (y2b + col) : (z2b + (col - N_CLS));
#pragma unroll
        for (int rr = 0; rr < 4; ++rr) {
            int row = m0 + q * 4 + rr;
            dst[(size_t)row * HID] = f2b(acc[rr]);   // stride 64 (padded)
        }
    }
}

// ---------------------------------------------------------------------------
// agg2 + log_softmax. ONE GROUP = ONE NODE (4 nodes/wave); softmax reduces
// stay inside the 16-lane group (shfl_xor 1,2,4,8). Pad cols masked to -inf.
// ---------------------------------------------------------------------------
__global__ void agg2_kernel(const int* __restrict__ rowptr,
                            const int* __restrict__ csr,
                            const ushort_t* __restrict__ y2b,
                            const ushort_t* __restrict__ z2b,
                            const float* __restrict__ b2,
                            float* __restrict__ out) {
    int gid = blockIdx.x * blockDim.x + threadIdx.x;
    int wave = gid >> 6, lane = gid & 63;
    int g = lane >> 4, l = lane & 15;
    int n = wave * 4 + g;
    if (n >= N_NODES) return;
    int beg = rowptr[n], end = rowptr[n + 1];
    float a0 = 0.f, a1 = 0.f, a2 = 0.f, a3 = 0.f;
    int i = beg;
    for (; i + 1 < end; i += 2) {
        int s0 = csr[i], s1 = csr[i + 1];
        ushort4 v0 = *(const ushort4*)(y2b + (size_t)s0 * HID + l * 4);
        ushort4 v1 = *(const ushort4*)(y2b + (size_t)s1 * HID + l * 4);
        a0 += b2f(v0.x) + b2f(v1.x);
        a1 += b2f(v0.y) + b2f(v1.y);
        a2 += b2f(v0.z) + b2f(v1.z);
        a3 += b2f(v0.w) + b2f(v1.w);
    }
    if (i < end) {
        ushort4 v = *(const ushort4*)(y2b + (size_t)csr[i] * HID + l * 4);
        a0 += b2f(v.x); a1 += b2f(v.y); a2 += b2f(v.z); a3 += b2f(v.w);
    }
    float inv = 1.0f / fmaxf((float)(end - beg), 1.0f);
    int c0 = l * 4;
    float4 bb = (l < 10) ? *(const float4*)(b2 + c0)
                         : make_float4(0.f, 0.f, 0.f, 0.f);
    ushort4 zz = *(const ushort4*)(z2b + (size_t)n * HID + c0);
    float v0 = (c0 + 0 < N_CLS) ? fmaf(a0, inv, bb.x + b2f(zz.x)) : -INFINITY;
    float v1 = (c0 + 1 < N_CLS) ? fmaf(a1, inv, bb.y + b2f(zz.y)) : -INFINITY;
    float v2 = (c0 + 2 < N_CLS) ? fmaf(a2, inv, bb.z + b2f(zz.z)) : -INFINITY;
    float v3 = (c0 + 3 < N_CLS) ? fmaf(a3, inv, bb.w + b2f(zz.w)) : -INFINITY;

    float m = fmaxf(fmaxf(v0, v1), fmaxf(v2, v3));
#pragma unroll
    for (int off = 1; off < 16; off <<= 1)
        m = fmaxf(m, __shfl_xor(m, off, 64));
    float s = 0.f;
    if (v0 > -INFINITY) s += expf(v0 - m);
    if (v1 > -INFINITY) s += expf(v1 - m);
    if (v2 > -INFINITY) s += expf(v2 - m);
    if (v3 > -INFINITY) s += expf(v3 - m);
#pragma unroll
    for (int off = 1; off < 16; off <<= 1)
        s += __shfl_xor(s, off, 64);
    float ls = logf(s);
    if (l < 10) {
        float4 o = make_float4(v0 - m - ls, v1 - m - ls, v2 - m - ls, v3 - m - ls);
        *(float4*)(out + (size_t)n * N_CLS + c0) = o;
    }
}

extern "C" void kernel_launch(void* const* d_in, const int* in_sizes, int n_in,
                              void* d_out, int out_size, void* d_ws, size_t ws_size,
                              hipStream_t stream) {
    const float* x   = (const float*)d_in[0];
    const int*   ei  = (const int*)d_in[1];
    const float* W1l = (const float*)d_in[2];
    const float* b1  = (const float*)d_in[3];
    const float* W1r = (const float*)d_in[4];
    const float* W2l = (const float*)d_in[5];
    const float* b2  = (const float*)d_in[6];
    const float* W2r = (const float*)d_in[7];
    float* out = (float*)d_out;
    const int E = in_sizes[1] / 2;
    const int nblk = (E + EPB - 1) / EPB;

    char* p = (char*)d_ws;
    auto take = [&](size_t bytes) {
        char* q = p;
        p += (bytes + 15) & ~(size_t)15;
        return (void*)q;
    };
    int* rowptr     = (int*)take(sizeof(int) * (N_NODES + 4));
    int* blockHist  = (int*)take(sizeof(int) * (size_t)nblk * NB);
    int* blockBase  = (int*)take(sizeof(int) * (size_t)nblk * NB);
    int* btot       = (int*)take(sizeof(int) * NB);
    int* boff       = (int*)take(sizeof(int) * NB);
    uint_t* pairs   = (uint_t*)take(sizeof(uint_t) * (size_t)E);
    int* csr        = (int*)take(sizeof(int) * (size_t)E);
    ushort_t* W1t   = (ushort_t*)take(sizeof(ushort_t) * 128 * F_IN);
    ushort_t* W2t   = (ushort_t*)take(sizeof(ushort_t) * 80 * HID);
    ushort_t* y1b   = (ushort_t*)take(sizeof(ushort_t) * (size_t)N_NODES * HID);
    ushort_t* z1b   = (ushort_t*)take(sizeof(ushort_t) * (size_t)N_NODES * HID);
    ushort_t* hb    = (ushort_t*)take(sizeof(ushort_t) * (size_t)N_NODES * HID);
    ushort_t* y2b = y1b;   // stride-64 padded; y1b/z1b dead after agg1
    ushort_t* z2b = z1b;

    const int B = 256;

    block_hist_kernel<<<nblk, 256, 0, stream>>>(ei, E, blockHist);
    col_scan_kernel<<<NB, 256, 0, stream>>>(blockHist, nblk, blockBase, btot);
    bucket_scan_kernel<<<1, 256, 0, stream>>>(btot, boff, rowptr);
    scatter_pairs_kernel<<<nblk, 256, 0, stream>>>(ei, E, blockBase, boff, pairs);
    bucket_sort_kernel<<<NB, BSZ, 0, stream>>>(pairs, boff, btot, rowptr, csr);

    cvt_w_kernel<<<(128 * F_IN + 80 * HID + B - 1) / B, B, 0, stream>>>(
        W1l, W1r, W2l, W2r, W1t, W2t);

    int t_mfma = MT * 64;
    int t_agg = (N_NODES / 4) * 64;     // 4 nodes per wave

    gemm1_mfma_kernel<<<(t_mfma + B - 1) / B, B, 0, stream>>>(x, W1t, y1b, z1b);
    agg1_kernel<<<(t_agg + B - 1) / B, B, 0, stream>>>(rowptr, csr, y1b, z1b, b1, hb);
    gemm2_mfma_kernel<<<(t_mfma + B - 1) / B, B, 0, stream>>>(hb, W2t, y2b, z2b);
    agg2_kernel<<<(t_agg + B - 1) / B, B, 0, stream>>>(rowptr, csr, y2b, z2b, b2, out);
}

// Round 10
// 271.622 us; speedup vs baseline: 1.1479x; 1.1228x over previous
//
#include <hip/hip_runtime.h>
#include <math.h>

#define N_NODES 100000
#define F_IN    128
#define HID     64
#define N_CLS   40
#define MT      (N_NODES / 16)                  // 6250 M-tiles of 16 nodes

#define BSHIFT  9
#define BSZ     512                              // dsts per coarse bucket
#define NB      ((N_NODES + BSZ - 1) / BSZ)      // 196 buckets
#define EPB     4096                             // edges per block in sort passes

typedef __attribute__((ext_vector_type(8))) short bf8_t;   // 8 bf16 (4 VGPR)
typedef __attribute__((ext_vector_type(4))) float f4_t;    // MFMA C/D frag
typedef __attribute__((ext_vector_type(2))) float f2v_t;

typedef unsigned short ushort_t;
typedef unsigned int uint_t;
typedef unsigned char uchar_t;

__device__ __forceinline__ ushort_t f2b(float f) {   // f32 -> bf16 RNE
    union { float f; uint_t u; } c; c.f = f;
    uint_t u = c.u + 0x7FFFu + ((c.u >> 16) & 1u);
    return (ushort_t)(u >> 16);
}
__device__ __forceinline__ float b2f(ushort_t h) {
    union { uint_t u; float f; } c; c.u = ((uint_t)h) << 16;
    return c.f;
}

// ---- fp8 e4m3 (OCP) helpers: HW cvt if available, manual fallback ---------
#if defined(__has_builtin)
#if __has_builtin(__builtin_amdgcn_cvt_pk_f32_fp8) && __has_builtin(__builtin_amdgcn_cvt_pk_fp8_f32)
#define HAVE_FP8_HW 1
#endif
#endif

__device__ __forceinline__ uchar_t fp8_enc(float v) {
#ifdef HAVE_FP8_HW
    return (uchar_t)(__builtin_amdgcn_cvt_pk_fp8_f32(v, v, 0, false) & 0xff);
#else
    // manual e4m3fn, round-to-nearest (ties away ok for our tolerance)
    union { float f; uint_t u; } c; c.f = v;
    uint_t s = c.u >> 31;
    float av = fabsf(v);
    if (av > 448.f) av = 448.f;
    int e;
    float m = frexpf(av, &e);          // av = m * 2^e, m in [0.5,1)
    int ee = e + 6;                    // biased for e4m3 (bias 7, m in [1,2))
    uchar_t r;
    if (av == 0.f) r = 0;
    else if (ee <= 0) {                // denormal
        int q = (int)(av * 512.f + 0.5f);   // units of 2^-9
        if (q > 7) q = 7;
        r = (uchar_t)q;
    } else {
        int q = (int)(m * 16.f + 0.5f);     // m*16 in [8,16]
        if (q == 16) { q = 8; ee += 1; }
        if (ee > 15) { ee = 15; q = 15; }   // clamp toward max finite
        r = (uchar_t)((ee << 3) | (q & 7));
    }
    return r | (uchar_t)(s << 7);
#endif
}

__device__ __forceinline__ f2v_t fp8x2_dec_lo(uint_t w) {
#ifdef HAVE_FP8_HW
    return __builtin_amdgcn_cvt_pk_f32_fp8(w, false);
#else
    f2v_t r;
    for (int k = 0; k < 2; ++k) {
        uchar_t b = (w >> (8 * k)) & 0xff;
        uint_t s = (b >> 7) & 1, e = (b >> 3) & 15, m = b & 7;
        float f;
        if (e) { union { uint_t u; float ff; } c;
                 c.u = (s << 31) | ((e + 120) << 23) | (m << 20); f = c.ff; }
        else   { f = (float)m * 0.001953125f; if (s) f = -f; }
        r[k] = f;
    }
    return r;
#endif
}
__device__ __forceinline__ f2v_t fp8x2_dec_hi(uint_t w) {
#ifdef HAVE_FP8_HW
    return __builtin_amdgcn_cvt_pk_f32_fp8(w, true);
#else
    return fp8x2_dec_lo(w >> 16);
#endif
}

// ---------------------------------------------------------------------------
// Sort pass 1: per-block LDS histogram over 196 coarse buckets (dst >> 9).
// ---------------------------------------------------------------------------
__global__ void block_hist_kernel(const int* __restrict__ ei, int E,
                                  int* __restrict__ blockHist) {
    __shared__ int cnt[NB];
    int t = threadIdx.x, blk = blockIdx.x;
    for (int i = t; i < NB; i += 256) cnt[i] = 0;
    __syncthreads();
    int e0 = blk * EPB;
#pragma unroll
    for (int i = 0; i < EPB / 256; ++i) {
        int e = e0 + i * 256 + t;
        if (e < E) atomicAdd(&cnt[ei[E + e] >> BSHIFT], 1);
    }
    __syncthreads();
    for (int i = t; i < NB; i += 256) blockHist[blk * NB + i] = cnt[i];
}

// ---------------------------------------------------------------------------
// Sort pass 2: per-bin exclusive scan down the blocks.
// ---------------------------------------------------------------------------
__global__ void col_scan_kernel(const int* __restrict__ blockHist, int nblk,
                                int* __restrict__ blockBase,
                                int* __restrict__ btot) {
    __shared__ int ss[256];
    __shared__ int carry;
    int bin = blockIdx.x, t = threadIdx.x;
    if (t == 0) carry = 0;
    __syncthreads();
    for (int c0 = 0; c0 < nblk; c0 += 256) {
        int b = c0 + t;
        int v = (b < nblk) ? blockHist[b * NB + bin] : 0;
        ss[t] = v;
        __syncthreads();
        for (int off = 1; off < 256; off <<= 1) {
            int u = (t >= off) ? ss[t - off] : 0;
            __syncthreads();
            ss[t] += u;
            __syncthreads();
        }
        if (b < nblk) blockBase[b * NB + bin] = carry + ss[t] - v;
        __syncthreads();
        if (t == 255) carry += ss[255];
        __syncthreads();
    }
    if (t == 0) btot[bin] = carry;
}

// ---------------------------------------------------------------------------
// Sort pass 3: exclusive scan over 196 bucket totals; rowptr[N] = E.
// ---------------------------------------------------------------------------
__global__ void bucket_scan_kernel(const int* __restrict__ btot,
                                   int* __restrict__ boff,
                                   int* __restrict__ rowptr) {
    __shared__ int ss[256];
    int t = threadIdx.x;
    int v = (t < NB) ? btot[t] : 0;
    ss[t] = v;
    __syncthreads();
    for (int off = 1; off < 256; off <<= 1) {
        int u = (t >= off) ? ss[t - off] : 0;
        __syncthreads();
        ss[t] += u;
        __syncthreads();
    }
    if (t < NB) boff[t] = ss[t] - v;
    if (t == NB - 1) rowptr[N_NODES] = ss[t];
}

// ---------------------------------------------------------------------------
// Sort pass 4: scatter packed (src<<9 | dst&511) into coarse-bucket order.
// ---------------------------------------------------------------------------
__global__ void scatter_pairs_kernel(const int* __restrict__ ei, int E,
                                     const int* __restrict__ blockBase,
                                     const int* __restrict__ boff,
                                     uint_t* __restrict__ pairs) {
    __shared__ int cur[NB];
    __shared__ int base[NB];
    int t = threadIdx.x, blk = blockIdx.x;
    for (int i = t; i < NB; i += 256) {
        cur[i] = 0;
        base[i] = boff[i] + blockBase[blk * NB + i];
    }
    __syncthreads();
    int e0 = blk * EPB;
#pragma unroll
    for (int i = 0; i < EPB / 256; ++i) {
        int e = e0 + i * 256 + t;
        if (e < E) {
            int src = ei[e];
            int dst = ei[E + e];
            int bin = dst >> BSHIFT;
            int r = atomicAdd(&cur[bin], 1);   // LDS atomic
            pairs[base[bin] + r] = ((uint_t)src << BSHIFT) | (uint_t)(dst & (BSZ - 1));
        }
    }
}

// ---------------------------------------------------------------------------
// Sort pass 5: per-bucket fine sort. rowptr + contiguous csr region.
// ---------------------------------------------------------------------------
__global__ void bucket_sort_kernel(const uint_t* __restrict__ pairs,
                                   const int* __restrict__ boff,
                                   const int* __restrict__ btot,
                                   int* __restrict__ rowptr,
                                   int* __restrict__ csr) {
    __shared__ int hist[BSZ];
    __shared__ int lofs[BSZ];
    int bin = blockIdx.x, t = threadIdx.x;
    int base = boff[bin], cnt = btot[bin];
    hist[t] = 0;
    __syncthreads();
    for (int i = t; i < cnt; i += BSZ)
        atomicAdd(&hist[pairs[base + i] & (BSZ - 1)], 1);
    __syncthreads();
    int v = hist[t];
    lofs[t] = v;
    __syncthreads();
    for (int off = 1; off < BSZ; off <<= 1) {
        int u = (t >= off) ? lofs[t - off] : 0;
        __syncthreads();
        lofs[t] += u;
        __syncthreads();
    }
    int excl = lofs[t] - v;
    int d_global = (bin << BSHIFT) + t;
    if (d_global < N_NODES) rowptr[d_global] = base + excl;
    __syncthreads();
    lofs[t] = excl;
    hist[t] = 0;
    __syncthreads();
    for (int i = t; i < cnt; i += BSZ) {
        uint_t p = pairs[base + i];
        int lb = p & (BSZ - 1);
        int r = atomicAdd(&hist[lb], 1);
        csr[base + lofs[lb] + r] = (int)(p >> BSHIFT);
    }
}

// ---------------------------------------------------------------------------
// cvt_w: bf16 [n][k]-major weight tensors.
// ---------------------------------------------------------------------------
__global__ void cvt_w_kernel(const float* __restrict__ W1l,
                             const float* __restrict__ W1r,
                             const float* __restrict__ W2l,
                             const float* __restrict__ W2r,
                             ushort_t* __restrict__ W1t,
                             ushort_t* __restrict__ W2t) {
    int t = blockIdx.x * blockDim.x + threadIdx.x;
    if (t < 128 * F_IN) {
        int n = t / F_IN, k = t - n * F_IN;
        float v = (n < HID) ? W1l[k * HID + n] : W1r[k * HID + (n - HID)];
        W1t[t] = f2b(v);
    } else if (t < 128 * F_IN + 80 * HID) {
        int u = t - 128 * F_IN;
        int n = u / HID, k = u - n * HID;
        float v = (n < N_CLS) ? W2l[k * N_CLS + n] : W2r[k * N_CLS + (n - N_CLS)];
        W2t[u] = f2b(v);
    }
}

// ---------------------------------------------------------------------------
// gemm1_mfma: y1(fp8) | z1(bf16) = x @ [W1_l|W1_r]  via mfma 16x16x32 bf16.
// Messages y1 stored as fp8 e4m3, 64 B rows (1 cache line).
// ---------------------------------------------------------------------------
__global__ void gemm1_mfma_kernel(const float* __restrict__ x,
                                  const ushort_t* __restrict__ W1t,
                                  uchar_t* __restrict__ y1f8,
                                  ushort_t* __restrict__ z1b) {
    int gid = blockIdx.x * blockDim.x + threadIdx.x;
    int wave = gid >> 6, lane = gid & 63;
    if (wave >= MT) return;
    int m0 = wave * 16;
    int r = lane & 15, q = lane >> 4;

    const float* xr = x + (size_t)(m0 + r) * F_IN + q * 8;
    bf8_t a[4];
#pragma unroll
    for (int kt = 0; kt < 4; ++kt) {
        float4 u = *(const float4*)(xr + kt * 32);
        float4 v = *(const float4*)(xr + kt * 32 + 4);
        bf8_t t;
        t[0] = (short)f2b(u.x); t[1] = (short)f2b(u.y);
        t[2] = (short)f2b(u.z); t[3] = (short)f2b(u.w);
        t[4] = (short)f2b(v.x); t[5] = (short)f2b(v.y);
        t[6] = (short)f2b(v.z); t[7] = (short)f2b(v.w);
        a[kt] = t;
    }
#pragma unroll
    for (int tn = 0; tn < 8; ++tn) {
        const ushort_t* wr = W1t + (size_t)(tn * 16 + r) * F_IN + q * 8;
        f4_t acc = {0.f, 0.f, 0.f, 0.f};
#pragma unroll
        for (int kt = 0; kt < 4; ++kt) {
            bf8_t b = *(const bf8_t*)(wr + kt * 32);
            acc = __builtin_amdgcn_mfma_f32_16x16x32_bf16(a[kt], b, acc, 0, 0, 0);
        }
        int col = tn * 16 + r;
        if (col < HID) {
#pragma unroll
            for (int rr = 0; rr < 4; ++rr) {
                int row = m0 + q * 4 + rr;
                y1f8[(size_t)row * HID + col] = fp8_enc(acc[rr]);
            }
        } else {
#pragma unroll
            for (int rr = 0; rr < 4; ++rr) {
                int row = m0 + q * 4 + rr;
                z1b[(size_t)row * HID + (col - HID)] = f2b(acc[rr]);
            }
        }
    }
}

// ---------------------------------------------------------------------------
// agg1: h = relu(mean y1[src] + b1 + z1).  One 16-lane group = one node
// (4 nodes/wave); lane l loads a uint = 4 fp8 cols (4l..4l+3); row = 64 B.
// ---------------------------------------------------------------------------
__global__ void agg1_kernel(const int* __restrict__ rowptr,
                            const int* __restrict__ csr,
                            const uchar_t* __restrict__ y1f8,
                            const ushort_t* __restrict__ z1b,
                            const float* __restrict__ b1,
                            ushort_t* __restrict__ hb) {
    int gid = blockIdx.x * blockDim.x + threadIdx.x;
    int wave = gid >> 6, lane = gid & 63;
    int g = lane >> 4, l = lane & 15;
    int n = wave * 4 + g;                 // N_NODES % 4 == 0
    if (n >= N_NODES) return;
    int beg = rowptr[n], end = rowptr[n + 1];
    float a0 = 0.f, a1 = 0.f, a2 = 0.f, a3 = 0.f;
    int i = beg;
    for (; i + 1 < end; i += 2) {
        int s0 = csr[i], s1 = csr[i + 1];
        uint_t w0 = *(const uint_t*)(y1f8 + (size_t)s0 * HID + l * 4);
        uint_t w1 = *(const uint_t*)(y1f8 + (size_t)s1 * HID + l * 4);
        f2v_t p0 = fp8x2_dec_lo(w0), p1 = fp8x2_dec_hi(w0);
        f2v_t q0 = fp8x2_dec_lo(w1), q1 = fp8x2_dec_hi(w1);
        a0 += p0[0] + q0[0];
        a1 += p0[1] + q0[1];
        a2 += p1[0] + q1[0];
        a3 += p1[1] + q1[1];
    }
    if (i < end) {
        uint_t w = *(const uint_t*)(y1f8 + (size_t)csr[i] * HID + l * 4);
        f2v_t p0 = fp8x2_dec_lo(w), p1 = fp8x2_dec_hi(w);
        a0 += p0[0]; a1 += p0[1]; a2 += p1[0]; a3 += p1[1];
    }
    float inv = 1.0f / fmaxf((float)(end - beg), 1.0f);
    float4 bb = *(const float4*)(b1 + l * 4);
    ushort4 zz = *(const ushort4*)(z1b + (size_t)n * HID + l * 4);
    float r0 = fmaxf(fmaf(a0, inv, bb.x + b2f(zz.x)), 0.f);
    float r1 = fmaxf(fmaf(a1, inv, bb.y + b2f(zz.y)), 0.f);
    float r2 = fmaxf(fmaf(a2, inv, bb.z + b2f(zz.z)), 0.f);
    float r3 = fmaxf(fmaf(a3, inv, bb.w + b2f(zz.w)), 0.f);
    ushort4 o;
    o.x = f2b(r0); o.y = f2b(r1); o.z = f2b(r2); o.w = f2b(r3);
    *(ushort4*)(hb + (size_t)n * HID + l * 4) = o;
}

// ---------------------------------------------------------------------------
// gemm2_mfma: y2(fp8, 64 B padded rows) | z2(bf16, stride 64) = h @ [W2l|W2r].
// ---------------------------------------------------------------------------
__global__ void gemm2_mfma_kernel(const ushort_t* __restrict__ hb,
                                  const ushort_t* __restrict__ W2t,
                                  uchar_t* __restrict__ y2f8,
                                  ushort_t* __restrict__ z2b) {
    int gid = blockIdx.x * blockDim.x + threadIdx.x;
    int wave = gid >> 6, lane = gid & 63;
    if (wave >= MT) return;
    int m0 = wave * 16;
    int r = lane & 15, q = lane >> 4;

    const ushort_t* hr = hb + (size_t)(m0 + r) * HID + q * 8;
    bf8_t a[2];
#pragma unroll
    for (int kt = 0; kt < 2; ++kt)
        a[kt] = *(const bf8_t*)(hr + kt * 32);

#pragma unroll
    for (int tn = 0; tn < 5; ++tn) {
        const ushort_t* wr = W2t + (size_t)(tn * 16 + r) * HID + q * 8;
        f4_t acc = {0.f, 0.f, 0.f, 0.f};
#pragma unroll
        for (int kt = 0; kt < 2; ++kt) {
            bf8_t b = *(const bf8_t*)(wr + kt * 32);
            acc = __builtin_amdgcn_mfma_f32_16x16x32_bf16(a[kt], b, acc, 0, 0, 0);
        }
        int col = tn * 16 + r;
        if (col < N_CLS) {
#pragma unroll
            for (int rr = 0; rr < 4; ++rr) {
                int row = m0 + q * 4 + rr;
                y2f8[(size_t)row * HID + col] = fp8_enc(acc[rr]);
            }
        } else {
#pragma unroll
            for (int rr = 0; rr < 4; ++rr) {
                int row = m0 + q * 4 + rr;
                z2b[(size_t)row * HID + (col - N_CLS)] = f2b(acc[rr]);
            }
        }
    }
}

// ---------------------------------------------------------------------------
// agg2 + log_softmax. One group = one node; fp8 rows (pad cols 40..63 are
// finite garbage, masked to -inf before the softmax reductions).
// ---------------------------------------------------------------------------
__global__ void agg2_kernel(const int* __restrict__ rowptr,
                            const int* __restrict__ csr,
                            const uchar_t* __restrict__ y2f8,
                            const ushort_t* __restrict__ z2b,
                            const float* __restrict__ b2,
                            float* __restrict__ out) {
    int gid = blockIdx.x * blockDim.x + threadIdx.x;
    int wave = gid >> 6, lane = gid & 63;
    int g = lane >> 4, l = lane & 15;
    int n = wave * 4 + g;
    if (n >= N_NODES) return;
    int beg = rowptr[n], end = rowptr[n + 1];
    float a0 = 0.f, a1 = 0.f, a2 = 0.f, a3 = 0.f;
    int i = beg;
    for (; i + 1 < end; i += 2) {
        int s0 = csr[i], s1 = csr[i + 1];
        uint_t w0 = *(const uint_t*)(y2f8 + (size_t)s0 * HID + l * 4);
        uint_t w1 = *(const uint_t*)(y2f8 + (size_t)s1 * HID + l * 4);
        f2v_t p0 = fp8x2_dec_lo(w0), p1 = fp8x2_dec_hi(w0);
        f2v_t q0 = fp8x2_dec_lo(w1), q1 = fp8x2_dec_hi(w1);
        a0 += p0[0] + q0[0];
        a1 += p0[1] + q0[1];
        a2 += p1[0] + q1[0];
        a3 += p1[1] + q1[1];
    }
    if (i < end) {
        uint_t w = *(const uint_t*)(y2f8 + (size_t)csr[i] * HID + l * 4);
        f2v_t p0 = fp8x2_dec_lo(w), p1 = fp8x2_dec_hi(w);
        a0 += p0[0]; a1 += p0[1]; a2 += p1[0]; a3 += p1[1];
    }
    float inv = 1.0f / fmaxf((float)(end - beg), 1.0f);
    int c0 = l * 4;
    float4 bb = (l < 10) ? *(const float4*)(b2 + c0)
                         : make_float4(0.f, 0.f, 0.f, 0.f);
    ushort4 zz = *(const ushort4*)(z2b + (size_t)n * HID + c0);
    float v0 = (c0 + 0 < N_CLS) ? fmaf(a0, inv, bb.x + b2f(zz.x)) : -INFINITY;
    float v1 = (c0 + 1 < N_CLS) ? fmaf(a1, inv, bb.y + b2f(zz.y)) : -INFINITY;
    float v2 = (c0 + 2 < N_CLS) ? fmaf(a2, inv, bb.z + b2f(zz.z)) : -INFINITY;
    float v3 = (c0 + 3 < N_CLS) ? fmaf(a3, inv, bb.w + b2f(zz.w)) : -INFINITY;

    float m = fmaxf(fmaxf(v0, v1), fmaxf(v2, v3));
#pragma unroll
    for (int off = 1; off < 16; off <<= 1)
        m = fmaxf(m, __shfl_xor(m, off, 64));
    float s = 0.f;
    if (v0 > -INFINITY) s += expf(v0 - m);
    if (v1 > -INFINITY) s += expf(v1 - m);
    if (v2 > -INFINITY) s += expf(v2 - m);
    if (v3 > -INFINITY) s += expf(v3 - m);
#pragma unroll
    for (int off = 1; off < 16; off <<= 1)
        s += __shfl_xor(s, off, 64);
    float ls = logf(s);
    if (l < 10) {
        float4 o = make_float4(v0 - m - ls, v1 - m - ls, v2 - m - ls, v3 - m - ls);
        *(float4*)(out + (size_t)n * N_CLS + c0) = o;
    }
}

extern "C" void kernel_launch(void* const* d_in, const int* in_sizes, int n_in,
                              void* d_out, int out_size, void* d_ws, size_t ws_size,
                              hipStream_t stream) {
    const float* x   = (const float*)d_in[0];
    const int*   ei  = (const int*)d_in[1];
    const float* W1l = (const float*)d_in[2];
    const float* b1  = (const float*)d_in[3];
    const float* W1r = (const float*)d_in[4];
    const float* W2l = (const float*)d_in[5];
    const float* b2  = (const float*)d_in[6];
    const float* W2r = (const float*)d_in[7];
    float* out = (float*)d_out;
    const int E = in_sizes[1] / 2;
    const int nblk = (E + EPB - 1) / EPB;

    char* p = (char*)d_ws;
    auto take = [&](size_t bytes) {
        char* q = p;
        p += (bytes + 15) & ~(size_t)15;
        return (void*)q;
    };
    int* rowptr     = (int*)take(sizeof(int) * (N_NODES + 4));
    int* blockHist  = (int*)take(sizeof(int) * (size_t)nblk * NB);
    int* blockBase  = (int*)take(sizeof(int) * (size_t)nblk * NB);
    int* btot       = (int*)take(sizeof(int) * NB);
    int* boff       = (int*)take(sizeof(int) * NB);
    uint_t* pairs   = (uint_t*)take(sizeof(uint_t) * (size_t)E);
    int* csr        = (int*)take(sizeof(int) * (size_t)E);
    ushort_t* W1t   = (ushort_t*)take(sizeof(ushort_t) * 128 * F_IN);
    ushort_t* W2t   = (ushort_t*)take(sizeof(ushort_t) * 80 * HID);
    uchar_t* y1f8   = (uchar_t*)take(sizeof(uchar_t) * (size_t)N_NODES * HID);
    ushort_t* z1b   = (ushort_t*)take(sizeof(ushort_t) * (size_t)N_NODES * HID);
    ushort_t* hb    = (ushort_t*)take(sizeof(ushort_t) * (size_t)N_NODES * HID);
    uchar_t* y2f8 = y1f8;   // dead after agg1; same N×64 B footprint
    ushort_t* z2b = z1b;    // dead after agg1; stride-64 rows, 40 real cols

    const int B = 256;

    block_hist_kernel<<<nblk, 256, 0, stream>>>(ei, E, blockHist);
    col_scan_kernel<<<NB, 256, 0, stream>>>(blockHist, nblk, blockBase, btot);
    bucket_scan_kernel<<<1, 256, 0, stream>>>(btot, boff, rowptr);
    scatter_pairs_kernel<<<nblk, 256, 0, stream>>>(ei, E, blockBase, boff, pairs);
    bucket_sort_kernel<<<NB, BSZ, 0, stream>>>(pairs, boff, btot, rowptr, csr);

    cvt_w_kernel<<<(128 * F_IN + 80 * HID + B - 1) / B, B, 0, stream>>>(
        W1l, W1r, W2l, W2r, W1t, W2t);

    int t_mfma = MT * 64;
    int t_agg = (N_NODES / 4) * 64;     // 4 nodes per wave

    gemm1_mfma_kernel<<<(t_mfma + B - 1) / B, B, 0, stream>>>(x, W1t, y1f8, z1b);
    agg1_kernel<<<(t_agg + B - 1) / B, B, 0, stream>>>(rowptr, csr, y1f8, z1b, b1, hb);
    gemm2_mfma_kernel<<<(t_mfma + B - 1) / B, B, 0, stream>>>(hb, W2t, y2f8, z2b);
    agg2_kernel<<<(t_agg + B - 1) / B, B, 0, stream>>>(rowptr, csr, y2f8, z2b, b2, out);
}

// Round 11
// 269.963 us; speedup vs baseline: 1.1550x; 1.0061x over previous
//
#include <hip/hip_runtime.h>
#include <math.h>

#define N_NODES 100000
#define F_IN    128
#define HID     64
#define N_CLS   40
#define MT      (N_NODES / 16)                  // 6250 M-tiles of 16 nodes

#define BSHIFT  9
#define BSZ     512                              // dsts per coarse bucket
#define NB      ((N_NODES + BSZ - 1) / BSZ)      // 196 buckets
#define EPB     4096                             // edges per block in sort passes

typedef __attribute__((ext_vector_type(8))) short bf8_t;   // 8 bf16 (4 VGPR)
typedef __attribute__((ext_vector_type(4))) float f4_t;    // MFMA C/D frag
typedef __attribute__((ext_vector_type(2))) float f2v_t;

typedef unsigned short ushort_t;
typedef unsigned int uint_t;
typedef unsigned char uchar_t;

__device__ __forceinline__ ushort_t f2b(float f) {   // f32 -> bf16 RNE
    union { float f; uint_t u; } c; c.f = f;
    uint_t u = c.u + 0x7FFFu + ((c.u >> 16) & 1u);
    return (ushort_t)(u >> 16);
}
__device__ __forceinline__ float b2f(ushort_t h) {
    union { uint_t u; float f; } c; c.u = ((uint_t)h) << 16;
    return c.f;
}

// ---- fp8 e4m3 (OCP) helpers: HW cvt if available, manual fallback ---------
#if defined(__has_builtin)
#if __has_builtin(__builtin_amdgcn_cvt_pk_f32_fp8) && __has_builtin(__builtin_amdgcn_cvt_pk_fp8_f32)
#define HAVE_FP8_HW 1
#endif
#endif

__device__ __forceinline__ uchar_t fp8_enc(float v) {
#ifdef HAVE_FP8_HW
    return (uchar_t)(__builtin_amdgcn_cvt_pk_fp8_f32(v, v, 0, false) & 0xff);
#else
    // manual e4m3fn, round-to-nearest (ties away ok for our tolerance)
    union { float f; uint_t u; } c; c.f = v;
    uint_t s = c.u >> 31;
    float av = fabsf(v);
    if (av > 448.f) av = 448.f;
    int e;
    float m = frexpf(av, &e);          // av = m * 2^e, m in [0.5,1)
    int ee = e + 6;                    // biased for e4m3 (bias 7, m in [1,2))
    uchar_t r;
    if (av == 0.f) r = 0;
    else if (ee <= 0) {                // denormal
        int q = (int)(av * 512.f + 0.5f);   // units of 2^-9
        if (q > 7) q = 7;
        r = (uchar_t)q;
    } else {
        int q = (int)(m * 16.f + 0.5f);     // m*16 in [8,16]
        if (q == 16) { q = 8; ee += 1; }
        if (ee > 15) { ee = 15; q = 15; }   // clamp toward max finite
        r = (uchar_t)((ee << 3) | (q & 7));
    }
    return r | (uchar_t)(s << 7);
#endif
}

__device__ __forceinline__ f2v_t fp8x2_dec_lo(uint_t w) {
#ifdef HAVE_FP8_HW
    return __builtin_amdgcn_cvt_pk_f32_fp8(w, false);
#else
    f2v_t r;
    for (int k = 0; k < 2; ++k) {
        uchar_t b = (w >> (8 * k)) & 0xff;
        uint_t s = (b >> 7) & 1, e = (b >> 3) & 15, m = b & 7;
        float f;
        if (e) { union { uint_t u; float ff; } c;
                 c.u = (s << 31) | ((e + 120) << 23) | (m << 20); f = c.ff; }
        else   { f = (float)m * 0.001953125f; if (s) f = -f; }
        r[k] = f;
    }
    return r;
#endif
}
__device__ __forceinline__ f2v_t fp8x2_dec_hi(uint_t w) {
#ifdef HAVE_FP8_HW
    return __builtin_amdgcn_cvt_pk_f32_fp8(w, true);
#else
    return fp8x2_dec_lo(w >> 16);
#endif
}

// ---------------------------------------------------------------------------
// Sort pass 1: per-block LDS histogram over 196 coarse buckets (dst >> 9).
// ---------------------------------------------------------------------------
__global__ void block_hist_kernel(const int* __restrict__ ei, int E,
                                  int* __restrict__ blockHist) {
    __shared__ int cnt[NB];
    int t = threadIdx.x, blk = blockIdx.x;
    for (int i = t; i < NB; i += 256) cnt[i] = 0;
    __syncthreads();
    int e0 = blk * EPB;
#pragma unroll
    for (int i = 0; i < EPB / 256; ++i) {
        int e = e0 + i * 256 + t;
        if (e < E) atomicAdd(&cnt[ei[E + e] >> BSHIFT], 1);
    }
    __syncthreads();
    for (int i = t; i < NB; i += 256) blockHist[blk * NB + i] = cnt[i];
}

// ---------------------------------------------------------------------------
// Sort pass 2: per-bin exclusive scan down the blocks.
// ---------------------------------------------------------------------------
__global__ void col_scan_kernel(const int* __restrict__ blockHist, int nblk,
                                int* __restrict__ blockBase,
                                int* __restrict__ btot) {
    __shared__ int ss[256];
    __shared__ int carry;
    int bin = blockIdx.x, t = threadIdx.x;
    if (t == 0) carry = 0;
    __syncthreads();
    for (int c0 = 0; c0 < nblk; c0 += 256) {
        int b = c0 + t;
        int v = (b < nblk) ? blockHist[b * NB + bin] : 0;
        ss[t] = v;
        __syncthreads();
        for (int off = 1; off < 256; off <<= 1) {
            int u = (t >= off) ? ss[t - off] : 0;
            __syncthreads();
            ss[t] += u;
            __syncthreads();
        }
        if (b < nblk) blockBase[b * NB + bin] = carry + ss[t] - v;
        __syncthreads();
        if (t == 255) carry += ss[255];
        __syncthreads();
    }
    if (t == 0) btot[bin] = carry;
}

// ---------------------------------------------------------------------------
// Sort pass 3: exclusive scan over 196 bucket totals; rowptr[N] = E.
// ---------------------------------------------------------------------------
__global__ void bucket_scan_kernel(const int* __restrict__ btot,
                                   int* __restrict__ boff,
                                   int* __restrict__ rowptr) {
    __shared__ int ss[256];
    int t = threadIdx.x;
    int v = (t < NB) ? btot[t] : 0;
    ss[t] = v;
    __syncthreads();
    for (int off = 1; off < 256; off <<= 1) {
        int u = (t >= off) ? ss[t - off] : 0;
        __syncthreads();
        ss[t] += u;
        __syncthreads();
    }
    if (t < NB) boff[t] = ss[t] - v;
    if (t == NB - 1) rowptr[N_NODES] = ss[t];
}

// ---------------------------------------------------------------------------
// Sort pass 4: scatter packed (src<<9 | dst&511) into coarse-bucket order.
// ---------------------------------------------------------------------------
__global__ void scatter_pairs_kernel(const int* __restrict__ ei, int E,
                                     const int* __restrict__ blockBase,
                                     const int* __restrict__ boff,
                                     uint_t* __restrict__ pairs) {
    __shared__ int cur[NB];
    __shared__ int base[NB];
    int t = threadIdx.x, blk = blockIdx.x;
    for (int i = t; i < NB; i += 256) {
        cur[i] = 0;
        base[i] = boff[i] + blockBase[blk * NB + i];
    }
    __syncthreads();
    int e0 = blk * EPB;
#pragma unroll
    for (int i = 0; i < EPB / 256; ++i) {
        int e = e0 + i * 256 + t;
        if (e < E) {
            int src = ei[e];
            int dst = ei[E + e];
            int bin = dst >> BSHIFT;
            int r = atomicAdd(&cur[bin], 1);   // LDS atomic
            pairs[base[bin] + r] = ((uint_t)src << BSHIFT) | (uint_t)(dst & (BSZ - 1));
        }
    }
}

// ---------------------------------------------------------------------------
// Sort pass 5: per-bucket fine sort. rowptr + contiguous csr region.
// ---------------------------------------------------------------------------
__global__ void bucket_sort_kernel(const uint_t* __restrict__ pairs,
                                   const int* __restrict__ boff,
                                   const int* __restrict__ btot,
                                   int* __restrict__ rowptr,
                                   int* __restrict__ csr) {
    __shared__ int hist[BSZ];
    __shared__ int lofs[BSZ];
    int bin = blockIdx.x, t = threadIdx.x;
    int base = boff[bin], cnt = btot[bin];
    hist[t] = 0;
    __syncthreads();
    for (int i = t; i < cnt; i += BSZ)
        atomicAdd(&hist[pairs[base + i] & (BSZ - 1)], 1);
    __syncthreads();
    int v = hist[t];
    lofs[t] = v;
    __syncthreads();
    for (int off = 1; off < BSZ; off <<= 1) {
        int u = (t >= off) ? lofs[t - off] : 0;
        __syncthreads();
        lofs[t] += u;
        __syncthreads();
    }
    int excl = lofs[t] - v;
    int d_global = (bin << BSHIFT) + t;
    if (d_global < N_NODES) rowptr[d_global] = base + excl;
    __syncthreads();
    lofs[t] = excl;
    hist[t] = 0;
    __syncthreads();
    for (int i = t; i < cnt; i += BSZ) {
        uint_t p = pairs[base + i];
        int lb = p & (BSZ - 1);
        int r = atomicAdd(&hist[lb], 1);
        csr[base + lofs[lb] + r] = (int)(p >> BSHIFT);
    }
}

// ---------------------------------------------------------------------------
// cvt_w: bf16 [n][k]-major weight tensors.
// ---------------------------------------------------------------------------
__global__ void cvt_w_kernel(const float* __restrict__ W1l,
                             const float* __restrict__ W1r,
                             const float* __restrict__ W2l,
                             const float* __restrict__ W2r,
                             ushort_t* __restrict__ W1t,
                             ushort_t* __restrict__ W2t) {
    int t = blockIdx.x * blockDim.x + threadIdx.x;
    if (t < 128 * F_IN) {
        int n = t / F_IN, k = t - n * F_IN;
        float v = (n < HID) ? W1l[k * HID + n] : W1r[k * HID + (n - HID)];
        W1t[t] = f2b(v);
    } else if (t < 128 * F_IN + 80 * HID) {
        int u = t - 128 * F_IN;
        int n = u / HID, k = u - n * HID;
        float v = (n < N_CLS) ? W2l[k * N_CLS + n] : W2r[k * N_CLS + (n - N_CLS)];
        W2t[u] = f2b(v);
    }
}

// ---------------------------------------------------------------------------
// gemm1_mfma: y1(fp8) | z1(bf16) = x @ [W1_l|W1_r]  via mfma 16x16x32 bf16.
// Messages y1 stored as fp8 e4m3, 64 B rows (1 cache line).
// ---------------------------------------------------------------------------
__global__ void gemm1_mfma_kernel(const float* __restrict__ x,
                                  const ushort_t* __restrict__ W1t,
                                  uchar_t* __restrict__ y1f8,
                                  ushort_t* __restrict__ z1b) {
    int gid = blockIdx.x * blockDim.x + threadIdx.x;
    int wave = gid >> 6, lane = gid & 63;
    if (wave >= MT) return;
    int m0 = wave * 16;
    int r = lane & 15, q = lane >> 4;

    const float* xr = x + (size_t)(m0 + r) * F_IN + q * 8;
    bf8_t a[4];
#pragma unroll
    for (int kt = 0; kt < 4; ++kt) {
        float4 u = *(const float4*)(xr + kt * 32);
        float4 v = *(const float4*)(xr + kt * 32 + 4);
        bf8_t t;
        t[0] = (short)f2b(u.x); t[1] = (short)f2b(u.y);
        t[2] = (short)f2b(u.z); t[3] = (short)f2b(u.w);
        t[4] = (short)f2b(v.x); t[5] = (short)f2b(v.y);
        t[6] = (short)f2b(v.z); t[7] = (short)f2b(v.w);
        a[kt] = t;
    }
#pragma unroll
    for (int tn = 0; tn < 8; ++tn) {
        const ushort_t* wr = W1t + (size_t)(tn * 16 + r) * F_IN + q * 8;
        f4_t acc = {0.f, 0.f, 0.f, 0.f};
#pragma unroll
        for (int kt = 0; kt < 4; ++kt) {
            bf8_t b = *(const bf8_t*)(wr + kt * 32);
            acc = __builtin_amdgcn_mfma_f32_16x16x32_bf16(a[kt], b, acc, 0, 0, 0);
        }
        int col = tn * 16 + r;
        if (col < HID) {
#pragma unroll
            for (int rr = 0; rr < 4; ++rr) {
                int row = m0 + q * 4 + rr;
                y1f8[(size_t)row * HID + col] = fp8_enc(acc[rr]);
            }
        } else {
#pragma unroll
            for (int rr = 0; rr < 4; ++rr) {
                int row = m0 + q * 4 + rr;
                z1b[(size_t)row * HID + (col - HID)] = f2b(acc[rr]);
            }
        }
    }
}

// ---------------------------------------------------------------------------
// agg1: h = relu(mean y1[src] + b1 + z1).  One 16-lane group = one node
// (4 nodes/wave); lane l loads a uint = 4 fp8 cols (4l..4l+3); row = 64 B.
// ---------------------------------------------------------------------------
__global__ void agg1_kernel(const int* __restrict__ rowptr,
                            const int* __restrict__ csr,
                            const uchar_t* __restrict__ y1f8,
                            const ushort_t* __restrict__ z1b,
                            const float* __restrict__ b1,
                            ushort_t* __restrict__ hb) {
    int gid = blockIdx.x * blockDim.x + threadIdx.x;
    int wave = gid >> 6, lane = gid & 63;
    int g = lane >> 4, l = lane & 15;
    int n = wave * 4 + g;                 // N_NODES % 4 == 0
    if (n >= N_NODES) return;
    int beg = rowptr[n], end = rowptr[n + 1];
    float a0 = 0.f, a1 = 0.f, a2 = 0.f, a3 = 0.f;
    int i = beg;
    for (; i + 1 < end; i += 2) {
        int s0 = csr[i], s1 = csr[i + 1];
        uint_t w0 = *(const uint_t*)(y1f8 + (size_t)s0 * HID + l * 4);
        uint_t w1 = *(const uint_t*)(y1f8 + (size_t)s1 * HID + l * 4);
        f2v_t p0 = fp8x2_dec_lo(w0), p1 = fp8x2_dec_hi(w0);
        f2v_t q0 = fp8x2_dec_lo(w1), q1 = fp8x2_dec_hi(w1);
        a0 += p0[0] + q0[0];
        a1 += p0[1] + q0[1];
        a2 += p1[0] + q1[0];
        a3 += p1[1] + q1[1];
    }
    if (i < end) {
        uint_t w = *(const uint_t*)(y1f8 + (size_t)csr[i] * HID + l * 4);
        f2v_t p0 = fp8x2_dec_lo(w), p1 = fp8x2_dec_hi(w);
        a0 += p0[0]; a1 += p0[1]; a2 += p1[0]; a3 += p1[1];
    }
    float inv = 1.0f / fmaxf((float)(end - beg), 1.0f);
    float4 bb = *(const float4*)(b1 + l * 4);
    ushort4 zz = *(const ushort4*)(z1b + (size_t)n * HID + l * 4);
    float r0 = fmaxf(fmaf(a0, inv, bb.x + b2f(zz.x)), 0.f);
    float r1 = fmaxf(fmaf(a1, inv, bb.y + b2f(zz.y)), 0.f);
    float r2 = fmaxf(fmaf(a2, inv, bb.z + b2f(zz.z)), 0.f);
    float r3 = fmaxf(fmaf(a3, inv, bb.w + b2f(zz.w)), 0.f);
    ushort4 o;
    o.x = f2b(r0); o.y = f2b(r1); o.z = f2b(r2); o.w = f2b(r3);
    *(ushort4*)(hb + (size_t)n * HID + l * 4) = o;
}

// ---------------------------------------------------------------------------
// gemm2_mfma: y2(fp8, 64 B padded rows) | z2(bf16, stride 64) = h @ [W2l|W2r].
// ---------------------------------------------------------------------------
__global__ void gemm2_mfma_kernel(const ushort_t* __restrict__ hb,
                                  const ushort_t* __restrict__ W2t,
                                  uchar_t* __restrict__ y2f8,
                                  ushort_t* __restrict__ z2b) {
    int gid = blockIdx.x * blockDim.x + threadIdx.x;
    int wave = gid >> 6, lane = gid & 63;
    if (wave >= MT) return;
    int m0 = wave * 16;
    int r = lane & 15, q = lane >> 4;

    const ushort_t* hr = hb + (size_t)(m0 + r) * HID + q * 8;
    bf8_t a[2];
#pragma unroll
    for (int kt = 0; kt < 2; ++kt)
        a[kt] = *(const bf8_t*)(hr + kt * 32);

#pragma unroll
    for (int tn = 0; tn < 5; ++tn) {
        const ushort_t* wr = W2t + (size_t)(tn * 16 + r) * HID + q * 8;
        f4_t acc = {0.f, 0.f, 0.f, 0.f};
#pragma unroll
        for (int kt = 0; kt < 2; ++kt) {
            bf8_t b = *(const bf8_t*)(wr + kt * 32);
            acc = __builtin_amdgcn_mfma_f32_16x16x32_bf16(a[kt], b, acc, 0, 0, 0);
        }
        int col = tn * 16 + r;
        if (col < N_CLS) {
#pragma unroll
            for (int rr = 0; rr < 4; ++rr) {
                int row = m0 + q * 4 + rr;
                y2f8[(size_t)row * HID + col] = fp8_enc(acc[rr]);
            }
        } else {
#pragma unroll
            for (int rr = 0; rr < 4; ++rr) {
                int row = m0 + q * 4 + rr;
                z2b[(size_t)row * HID + (col - N_CLS)] = f2b(acc[rr]);
            }
        }
    }
}

// ---------------------------------------------------------------------------
// agg2 + log_softmax. One group = one node; fp8 rows (pad cols 40..63 are
// finite garbage, masked to -inf before the softmax reductions).
// ---------------------------------------------------------------------------
__global__ void agg2_kernel(const int* __restrict__ rowptr,
                            const int* __restrict__ csr,
                            const uchar_t* __restrict__ y2f8,
                            const ushort_t* __restrict__ z2b,
                            const float* __restrict__ b2,
                            float* __restrict__ out) {
    int gid = blockIdx.x * blockDim.x + threadIdx.x;
    int wave = gid >> 6, lane = gid & 63;
    int g = lane >> 4, l = lane & 15;
    int n = wave * 4 + g;
    if (n >= N_NODES) return;
    int beg = rowptr[n], end = rowptr[n + 1];
    float a0 = 0.f, a1 = 0.f, a2 = 0.f, a3 = 0.f;
    int i = beg;
    for (; i + 1 < end; i += 2) {
        int s0 = csr[i], s1 = csr[i + 1];
        uint_t w0 = *(const uint_t*)(y2f8 + (size_t)s0 * HID + l * 4);
        uint_t w1 = *(const uint_t*)(y2f8 + (size_t)s1 * HID + l * 4);
        f2v_t p0 = fp8x2_dec_lo(w0), p1 = fp8x2_dec_hi(w0);
        f2v_t q0 = fp8x2_dec_lo(w1), q1 = fp8x2_dec_hi(w1);
        a0 += p0[0] + q0[0];
        a1 += p0[1] + q0[1];
        a2 += p1[0] + q1[0];
        a3 += p1[1] + q1[1];
    }
    if (i < end) {
        uint_t w = *(const uint_t*)(y2f8 + (size_t)csr[i] * HID + l * 4);
        f2v_t p0 = fp8x2_dec_lo(w), p1 = fp8x2_dec_hi(w);
        a0 += p0[0]; a1 += p0[1]; a2 += p1[0]; a3 += p1[1];
    }
    float inv = 1.0f / fmaxf((float)(end - beg), 1.0f);
    int c0 = l * 4;
    float4 bb = (l < 10) ? *(const float4*)(b2 + c0)
                         : make_float4(0.f, 0.f, 0.f, 0.f);
    ushort4 zz = *(const ushort4*)(z2b + (size_t)n * HID + c0);
    float v0 = (c0 + 0 < N_CLS) ? fmaf(a0, inv, bb.x + b2f(zz.x)) : -INFINITY;
    float v1 = (c0 + 1 < N_CLS) ? fmaf(a1, inv, bb.y + b2f(zz.y)) : -INFINITY;
    float v2 = (c0 + 2 < N_CLS) ? fmaf(a2, inv, bb.z + b2f(zz.z)) : -INFINITY;
    float v3 = (c0 + 3 < N_CLS) ? fmaf(a3, inv, bb.w + b2f(zz.w)) : -INFINITY;

    float m = fmaxf(fmaxf(v0, v1), fmaxf(v2, v3));
#pragma unroll
    for (int off = 1; off < 16; off <<= 1)
        m = fmaxf(m, __shfl_xor(m, off, 64));
    float s = 0.f;
    if (v0 > -INFINITY) s += expf(v0 - m);
    if (v1 > -INFINITY) s += expf(v1 - m);
    if (v2 > -INFINITY) s += expf(v2 - m);
    if (v3 > -INFINITY) s += expf(v3 - m);
#pragma unroll
    for (int off = 1; off < 16; off <<= 1)
        s += __shfl_xor(s, off, 64);
    float ls = logf(s);
    if (l < 10) {
        float4 o = make_float4(v0 - m - ls, v1 - m - ls, v2 - m - ls, v3 - m - ls);
        *(float4*)(out + (size_t)n * N_CLS + c0) = o;
    }
}

extern "C" void kernel_launch(void* const* d_in, const int* in_sizes, int n_in,
                              void* d_out, int out_size, void* d_ws, size_t ws_size,
                              hipStream_t stream) {
    const float* x   = (const float*)d_in[0];
    const int*   ei  = (const int*)d_in[1];
    const float* W1l = (const float*)d_in[2];
    const float* b1  = (const float*)d_in[3];
    const float* W1r = (const float*)d_in[4];
    const float* W2l = (const float*)d_in[5];
    const float* b2  = (const float*)d_in[6];
    const float* W2r = (const float*)d_in[7];
    float* out = (float*)d_out;
    const int E = in_sizes[1] / 2;
    const int nblk = (E + EPB - 1) / EPB;

    char* p = (char*)d_ws;
    auto take = [&](size_t bytes) {
        char* q = p;
        p += (bytes + 15) & ~(size_t)15;
        return (void*)q;
    };
    int* rowptr     = (int*)take(sizeof(int) * (N_NODES + 4));
    int* blockHist  = (int*)take(sizeof(int) * (size_t)nblk * NB);
    int* blockBase  = (int*)take(sizeof(int) * (size_t)nblk * NB);
    int* btot       = (int*)take(sizeof(int) * NB);
    int* boff       = (int*)take(sizeof(int) * NB);
    uint_t* pairs   = (uint_t*)take(sizeof(uint_t) * (size_t)E);
    int* csr        = (int*)take(sizeof(int) * (size_t)E);
    ushort_t* W1t   = (ushort_t*)take(sizeof(ushort_t) * 128 * F_IN);
    ushort_t* W2t   = (ushort_t*)take(sizeof(ushort_t) * 80 * HID);
    uchar_t* y1f8   = (uchar_t*)take(sizeof(uchar_t) * (size_t)N_NODES * HID);
    ushort_t* z1b   = (ushort_t*)take(sizeof(ushort_t) * (size_t)N_NODES * HID);
    ushort_t* hb    = (ushort_t*)take(sizeof(ushort_t) * (size_t)N_NODES * HID);
    uchar_t* y2f8 = y1f8;   // dead after agg1; same N×64 B footprint
    ushort_t* z2b = z1b;    // dead after agg1; stride-64 rows, 40 real cols

    const int B = 256;

    block_hist_kernel<<<nblk, 256, 0, stream>>>(ei, E, blockHist);
    col_scan_kernel<<<NB, 256, 0, stream>>>(blockHist, nblk, blockBase, btot);
    bucket_scan_kernel<<<1, 256, 0, stream>>>(btot, boff, rowptr);
    scatter_pairs_kernel<<<nblk, 256, 0, stream>>>(ei, E, blockBase, boff, pairs);
    bucket_sort_kernel<<<NB, BSZ, 0, stream>>>(pairs, boff, btot, rowptr, csr);

    cvt_w_kernel<<<(128 * F_IN + 80 * HID + B - 1) / B, B, 0, stream>>>(
        W1l, W1r, W2l, W2r, W1t, W2t);

    int t_mfma = MT * 64;
    int t_agg = (N_NODES / 4) * 64;     // 4 nodes per wave

    gemm1_mfma_kernel<<<(t_mfma + B - 1) / B, B, 0, stream>>>(x, W1t, y1f8, z1b);
    agg1_kernel<<<(t_agg + B - 1) / B, B, 0, stream>>>(rowptr, csr, y1f8, z1b, b1, hb);
    gemm2_mfma_kernel<<<(t_mfma + B - 1) / B, B, 0, stream>>>(hb, W2t, y2f8, z2b);
    agg2_kernel<<<(t_agg + B - 1) / B, B, 0, stream>>>(rowptr, csr, y2f8, z2b, b2, out);
}